// Round 14
// baseline (36.292 us; speedup 1.0000x reference)
//
#include <hip/hip_runtime.h>
#include <limits.h>
#include <stdint.h>

#define SCAN_BS  256
#define MOT_BS   256
#define WAVE_OBJ 64
#define WSLAB_F  (WAVE_OBJ * 21)   // 1344 floats = 5376 B per wave slab

// clang vector types (accepted by __builtin_nontemporal_store)
typedef float vf4 __attribute__((ext_vector_type(4)));
typedef float vf2 __attribute__((ext_vector_type(2)));

// ---- global->LDS DMA helpers (size must be a literal) ----
__device__ __forceinline__ void gload_lds16(const void* g, void* l) {
    __builtin_amdgcn_global_load_lds(
        (const __attribute__((address_space(1))) uint32_t*)g,
        (__attribute__((address_space(3))) uint32_t*)l, 16, 0, 0);
}
__device__ __forceinline__ void gload_lds4(const void* g, void* l) {
    __builtin_amdgcn_global_load_lds(
        (const __attribute__((address_space(1))) uint32_t*)g,
        (__attribute__((address_space(3))) uint32_t*)l, 4, 0, 0);
}

// ---------------- hierarchical scan, stage 1: per-chunk sums ----------------
__global__ __launch_bounds__(SCAN_BS) void chunk_sum_kernel(
    const int* __restrict__ counts, int C, int* __restrict__ chunkSum) {

    __shared__ int ws[SCAN_BS / 64];
    const int tid  = threadIdx.x;
    const int lane = tid & 63;
    const int wid  = tid >> 6;
    const int gid  = blockIdx.x * SCAN_BS + tid;

    int v = (gid < C) ? counts[gid] : 0;
    #pragma unroll
    for (int o = 32; o > 0; o >>= 1) v += __shfl_down(v, o, 64);
    if (lane == 0) ws[wid] = v;
    __syncthreads();
    if (tid == 0) chunkSum[blockIdx.x] = ws[0] + ws[1] + ws[2] + ws[3];
}

// ---------------- hierarchical scan, stage 2: scan + emit ----------------
__global__ __launch_bounds__(SCAN_BS) void scan_emit_kernel(
    const int* __restrict__ counts, const int* __restrict__ chunkSum,
    int C, int* __restrict__ offsets, int* __restrict__ waveCav) {

    __shared__ int cw[SCAN_BS / 64];
    __shared__ int wv[SCAN_BS / 64];

    const int tid  = threadIdx.x;
    const int lane = tid & 63;
    const int wid  = tid >> 6;
    const int b    = blockIdx.x;
    const int gid  = b * SCAN_BS + tid;

    int cs = 0;
    for (int j = tid; j < b; j += SCAN_BS) cs += chunkSum[j];
    #pragma unroll
    for (int o = 32; o > 0; o >>= 1) cs += __shfl_down(cs, o, 64);

    const int v = (gid < C) ? counts[gid] : 0;
    int inc = v;
    #pragma unroll
    for (int o = 1; o < 64; o <<= 1) {
        int t = __shfl_up(inc, o, 64);
        if (lane >= o) inc += t;
    }

    if (lane == 0)  cw[wid] = cs;
    if (lane == 63) wv[wid] = inc;
    __syncthreads();

    int base = 0;
    #pragma unroll
    for (int w = 0; w < SCAN_BS / 64; ++w) {
        base += cw[w];
        if (w < wid) base += wv[w];
    }

    if (gid < C) {
        const int end = base + inc;     // inclusive cumsum
        offsets[gid] = end;
        const int start = end - v;
        int s0 = ((start + WAVE_OBJ - 1) / WAVE_OBJ) * WAVE_OBJ;
        for (int s = s0; s < end; s += WAVE_OBJ) waveCav[s / WAVE_OBJ] = gid;
    }
}

// ---------------- main per-object kernel ----------------
// Per-wave DMA staging + branchless counting search (R12-proven) + WAVE-LOCAL
// drain (vmcnt-tracked, slabs wave-private) + nontemporal output stores.
//
// out layout (floats):
//   [0,       8N)  obj_input  [1,N,2,4]
//   [8N,     10N)  query      [1,N,1,2]
//   [10N,    12N)  time_encode[N,2]
//   [12N,    13N)  target_time_diff [N]

__global__ __launch_bounds__(MOT_BS) void motion_kernel(
    const float* __restrict__ bbx, const float* __restrict__ tint,
    const int* __restrict__ offsets, const int* __restrict__ waveCav,
    int C, int N, float* __restrict__ out) {

    __shared__ __align__(16) float sb[(MOT_BS / 64) * WSLAB_F];   // 21504 B -> 7 blocks/CU

    const int tid  = threadIdx.x;
    const int lane = tid & 63;
    const int wid  = tid >> 6;
    const int w    = blockIdx.x * (MOT_BS / 64) + wid;   // global wave id
    const int objBase = w * WAVE_OBJ;
    const int i = objBase + lane;
    const bool fullWave = (objBase + WAVE_OBJ <= N);

    int cav = 0;
    float t0, t1, t2;
    float x0, y0, x1, y1, x2, y2;

    if (fullWave) {
        // ---- wave-local DMA staging (fire-and-forget) ----
        const int c0 = waveCav[w];
        float* slab = sb + wid * WSLAB_F;
        const float* gw = bbx + (size_t)objBase * 21;    // objBase*84 B -> 16B aligned
        #pragma unroll
        for (int ch = 0; ch < 5; ++ch)
            gload_lds16((const void*)(gw + ch * 256 + lane * 4), (void*)(slab + ch * 256));
        gload_lds4((const void*)(gw + 1280 + lane), (void*)(slab + 1280));

        // offsets window in registers (wave spans cavs [c0, c0+63])
        const int cc   = c0 + lane;
        const int offv = (cc < C) ? offsets[cc] : INT_MAX;

        // branchless counting lower_bound: k = #entries <= i  (answer in [0,63])
        int k = 0;
        #pragma unroll
        for (int s = 32; s >= 1; s >>= 1) {
            const int vt = __shfl(offv, k + s - 1, 64);
            if (vt <= i) k += s;
        }
        cav = c0 + k;

        // per-lane time gather, overlapped with DMA flight
        t0 = tint[3 * cav + 0];
        t1 = tint[3 * cav + 1];
        t2 = tint[3 * cav + 2];

        // ---- wave-local drain: our DMA chunks (and the loads above) are done ----
        asm volatile("s_waitcnt vmcnt(0)" ::: "memory");
        __builtin_amdgcn_sched_barrier(0);

        // 6 LDS reads, stride 21 words -> 2 lanes/bank = conflict-free
        const float* bp = slab + lane * 21;
        x0 = bp[0];  y0 = bp[1];
        x1 = bp[7];  y1 = bp[8];
        x2 = bp[14]; y2 = bp[15];
    } else {
        // tail path (not hit when N % 64 == 0)
        if (i >= N) return;
        int lo = 0, hi = C;
        while (lo < hi) {
            const int mid = (lo + hi) >> 1;
            if (offsets[mid] > i) hi = mid; else lo = mid + 1;
        }
        cav = lo;
        t0 = tint[3 * cav + 0];
        t1 = tint[3 * cav + 1];
        t2 = tint[3 * cav + 2];
        const float* bp = bbx + (size_t)i * 21;
        x0 = bp[0];  y0 = bp[1];
        x1 = bp[7];  y1 = bp[8];
        x2 = bp[14]; y2 = bp[15];
    }

    // td_rep = [t2, t1, t0];  dt = time_encode
    const float dt0 = t1 - t2;
    const float dt1 = t0 - t1;

    // coords (flipped, normalized to last): c0v = f2-f0, c1v = f1-f0, c2v = 0
    const float c0x = x2 - x0, c0y = y2 - y0;
    const float c1x = x1 - x0, c1y = y1 - y0;

    const float d0x = c1x - c0x, d0y = c1y - c0y;
    const float d1x = 0.0f - c1x, d1y = 0.0f - c1y;

    const float s0x = d0x / dt0, s0y = d0y / dt0;
    const float s1x = d1x / dt1, s1y = d1y / dt1;

    const float last_len = 0.0f - (t1 - t0);
    const float safe_len = (last_len == 0.0f) ? 1.0f : last_len;
    const float exx = ((0.0f - c1x) * (0.0f - t0)) / safe_len;
    const float exy = ((0.0f - c1y) * (0.0f - t0)) / safe_len;
    const float qx = (last_len == 0.0f) ? 0.0f : exx;
    const float qy = (last_len == 0.0f) ? 0.0f : exy;

    // ---- nontemporal coalesced writes (out is write-once, never re-read) ----
    const size_t Ns = (size_t)N;
    vf4* oi = (vf4*)out;
    vf4 o0; o0.x = d0x; o0.y = d0y; o0.z = s0x; o0.w = s0y;
    vf4 o1; o1.x = d1x; o1.y = d1y; o1.z = s1x; o1.w = s1y;
    __builtin_nontemporal_store(o0, oi + (size_t)i * 2 + 0);
    __builtin_nontemporal_store(o1, oi + (size_t)i * 2 + 1);

    vf2* q = (vf2*)(out + 8 * Ns);
    vf2 qv; qv.x = qx; qv.y = qy;
    __builtin_nontemporal_store(qv, q + i);

    vf2* te = (vf2*)(out + 10 * Ns);
    vf2 tv; tv.x = dt0; tv.y = dt1;
    __builtin_nontemporal_store(tv, te + i);

    __builtin_nontemporal_store(0.0f - t0, out + 12 * Ns + (size_t)i);
}

// ---------------- launch ----------------

extern "C" void kernel_launch(void* const* d_in, const int* in_sizes, int n_in,
                              void* d_out, int out_size, void* d_ws, size_t ws_size,
                              hipStream_t stream) {
    const float* bbx  = (const float*)d_in[0];   // [N,3,7]
    const float* tint = (const float*)d_in[1];   // [C*3]
    const int*   cnt  = (const int*)d_in[2];     // [C]
    float* out = (float*)d_out;

    const int N = in_sizes[0] / 21;
    const int C = in_sizes[2];

    const int nb     = (C + SCAN_BS - 1) / SCAN_BS;
    const int nWaves = (N + WAVE_OBJ - 1) / WAVE_OBJ;
    const int nob    = (nWaves * WAVE_OBJ + MOT_BS - 1) / MOT_BS;

    // ws layout: offsets[C] | pad 64 | waveCav[nWaves] | pad 64 | chunkSum[nb]
    int* offsets  = (int*)d_ws;
    int* waveCav  = offsets + C + 64;
    int* chunkSum = waveCav + nWaves + 64;

    chunk_sum_kernel<<<nb, SCAN_BS, 0, stream>>>(cnt, C, chunkSum);
    scan_emit_kernel<<<nb, SCAN_BS, 0, stream>>>(cnt, chunkSum, C, offsets, waveCav);
    motion_kernel<<<nob, MOT_BS, 0, stream>>>(bbx, tint, offsets, waveCav, C, N, out);
}

// Round 15
// 34.495 us; speedup vs baseline: 1.0521x; 1.0521x over previous
//
#include <hip/hip_runtime.h>
#include <limits.h>
#include <stdint.h>

#define SCAN_BS  256
#define MOT_BS   256
#define WAVE_OBJ 64
#define WSLAB_F  (WAVE_OBJ * 21)   // 1344 floats = 5376 B per wave slab

// ---- global->LDS DMA helpers (size must be a literal) ----
__device__ __forceinline__ void gload_lds16(const void* g, void* l) {
    __builtin_amdgcn_global_load_lds(
        (const __attribute__((address_space(1))) uint32_t*)g,
        (__attribute__((address_space(3))) uint32_t*)l, 16, 0, 0);
}
__device__ __forceinline__ void gload_lds4(const void* g, void* l) {
    __builtin_amdgcn_global_load_lds(
        (const __attribute__((address_space(1))) uint32_t*)g,
        (__attribute__((address_space(3))) uint32_t*)l, 4, 0, 0);
}

// ---------------- hierarchical scan, stage 1: per-chunk sums ----------------
__global__ __launch_bounds__(SCAN_BS) void chunk_sum_kernel(
    const int* __restrict__ counts, int C, int* __restrict__ chunkSum) {

    __shared__ int ws[SCAN_BS / 64];
    const int tid  = threadIdx.x;
    const int lane = tid & 63;
    const int wid  = tid >> 6;
    const int gid  = blockIdx.x * SCAN_BS + tid;

    int v = (gid < C) ? counts[gid] : 0;
    #pragma unroll
    for (int o = 32; o > 0; o >>= 1) v += __shfl_down(v, o, 64);
    if (lane == 0) ws[wid] = v;
    __syncthreads();
    if (tid == 0) chunkSum[blockIdx.x] = ws[0] + ws[1] + ws[2] + ws[3];
}

// ---------------- hierarchical scan, stage 2: scan + emit ----------------
__global__ __launch_bounds__(SCAN_BS) void scan_emit_kernel(
    const int* __restrict__ counts, const int* __restrict__ chunkSum,
    int C, int* __restrict__ offsets, int* __restrict__ waveCav) {

    __shared__ int cw[SCAN_BS / 64];
    __shared__ int wv[SCAN_BS / 64];

    const int tid  = threadIdx.x;
    const int lane = tid & 63;
    const int wid  = tid >> 6;
    const int b    = blockIdx.x;
    const int gid  = b * SCAN_BS + tid;

    int cs = 0;
    for (int j = tid; j < b; j += SCAN_BS) cs += chunkSum[j];
    #pragma unroll
    for (int o = 32; o > 0; o >>= 1) cs += __shfl_down(cs, o, 64);

    const int v = (gid < C) ? counts[gid] : 0;
    int inc = v;
    #pragma unroll
    for (int o = 1; o < 64; o <<= 1) {
        int t = __shfl_up(inc, o, 64);
        if (lane >= o) inc += t;
    }

    if (lane == 0)  cw[wid] = cs;
    if (lane == 63) wv[wid] = inc;
    __syncthreads();

    int base = 0;
    #pragma unroll
    for (int w = 0; w < SCAN_BS / 64; ++w) {
        base += cw[w];
        if (w < wid) base += wv[w];
    }

    if (gid < C) {
        const int end = base + inc;     // inclusive cumsum
        offsets[gid] = end;
        const int start = end - v;
        int s0 = ((start + WAVE_OBJ - 1) / WAVE_OBJ) * WAVE_OBJ;
        for (int s = s0; s < end; s += WAVE_OBJ) waveCav[s / WAVE_OBJ] = gid;
    }
}

// ---------------- main per-object kernel ----------------
// Per-wave DMA staging + branchless counting search (R12-proven) + WAVE-LOCAL
// drain (correctness proven in R14). Regular cached stores (nt regressed, R14).
//
// out layout (floats):
//   [0,       8N)  obj_input  [1,N,2,4]
//   [8N,     10N)  query      [1,N,1,2]
//   [10N,    12N)  time_encode[N,2]
//   [12N,    13N)  target_time_diff [N]

__global__ __launch_bounds__(MOT_BS) void motion_kernel(
    const float* __restrict__ bbx, const float* __restrict__ tint,
    const int* __restrict__ offsets, const int* __restrict__ waveCav,
    int C, int N, float* __restrict__ out) {

    __shared__ __align__(16) float sb[(MOT_BS / 64) * WSLAB_F];   // 21504 B -> 7 blocks/CU

    const int tid  = threadIdx.x;
    const int lane = tid & 63;
    const int wid  = tid >> 6;
    const int w    = blockIdx.x * (MOT_BS / 64) + wid;   // global wave id
    const int objBase = w * WAVE_OBJ;
    const int i = objBase + lane;
    const bool fullWave = (objBase + WAVE_OBJ <= N);

    int cav = 0;
    float t0, t1, t2;
    float x0, y0, x1, y1, x2, y2;

    if (fullWave) {
        // ---- wave-local DMA staging (fire-and-forget) ----
        const int c0 = waveCav[w];
        float* slab = sb + wid * WSLAB_F;
        const float* gw = bbx + (size_t)objBase * 21;    // objBase*84 B -> 16B aligned
        #pragma unroll
        for (int ch = 0; ch < 5; ++ch)
            gload_lds16((const void*)(gw + ch * 256 + lane * 4), (void*)(slab + ch * 256));
        gload_lds4((const void*)(gw + 1280 + lane), (void*)(slab + 1280));

        // offsets window in registers (wave spans cavs [c0, c0+63])
        const int cc   = c0 + lane;
        const int offv = (cc < C) ? offsets[cc] : INT_MAX;

        // branchless counting lower_bound: k = #entries <= i  (answer in [0,63])
        int k = 0;
        #pragma unroll
        for (int s = 32; s >= 1; s >>= 1) {
            const int vt = __shfl(offv, k + s - 1, 64);
            if (vt <= i) k += s;
        }
        cav = c0 + k;

        // per-lane time gather, overlapped with DMA flight
        t0 = tint[3 * cav + 0];
        t1 = tint[3 * cav + 1];
        t2 = tint[3 * cav + 2];

        // ---- wave-local drain: our DMA chunks (and the loads above) are done ----
        asm volatile("s_waitcnt vmcnt(0)" ::: "memory");
        __builtin_amdgcn_sched_barrier(0);

        // 6 LDS reads, stride 21 words -> 2 lanes/bank = conflict-free
        const float* bp = slab + lane * 21;
        x0 = bp[0];  y0 = bp[1];
        x1 = bp[7];  y1 = bp[8];
        x2 = bp[14]; y2 = bp[15];
    } else {
        // tail path (not hit when N % 64 == 0)
        if (i >= N) return;
        int lo = 0, hi = C;
        while (lo < hi) {
            const int mid = (lo + hi) >> 1;
            if (offsets[mid] > i) hi = mid; else lo = mid + 1;
        }
        cav = lo;
        t0 = tint[3 * cav + 0];
        t1 = tint[3 * cav + 1];
        t2 = tint[3 * cav + 2];
        const float* bp = bbx + (size_t)i * 21;
        x0 = bp[0];  y0 = bp[1];
        x1 = bp[7];  y1 = bp[8];
        x2 = bp[14]; y2 = bp[15];
    }

    // td_rep = [t2, t1, t0];  dt = time_encode
    const float dt0 = t1 - t2;
    const float dt1 = t0 - t1;

    // coords (flipped, normalized to last): c0v = f2-f0, c1v = f1-f0, c2v = 0
    const float c0x = x2 - x0, c0y = y2 - y0;
    const float c1x = x1 - x0, c1y = y1 - y0;

    const float d0x = c1x - c0x, d0y = c1y - c0y;
    const float d1x = 0.0f - c1x, d1y = 0.0f - c1y;

    const float s0x = d0x / dt0, s0y = d0y / dt0;
    const float s1x = d1x / dt1, s1y = d1y / dt1;

    const float last_len = 0.0f - (t1 - t0);
    const float safe_len = (last_len == 0.0f) ? 1.0f : last_len;
    const float exx = ((0.0f - c1x) * (0.0f - t0)) / safe_len;
    const float exy = ((0.0f - c1y) * (0.0f - t0)) / safe_len;
    const float qx = (last_len == 0.0f) ? 0.0f : exx;
    const float qy = (last_len == 0.0f) ? 0.0f : exy;

    // ---- regular cached coalesced writes ----
    const size_t Ns = (size_t)N;
    float4* oi = (float4*)out;
    oi[(size_t)i * 2 + 0] = make_float4(d0x, d0y, s0x, s0y);
    oi[(size_t)i * 2 + 1] = make_float4(d1x, d1y, s1x, s1y);

    float2* q  = (float2*)(out + 8 * Ns);
    q[i] = make_float2(qx, qy);

    float2* te = (float2*)(out + 10 * Ns);
    te[i] = make_float2(dt0, dt1);

    out[12 * Ns + (size_t)i] = 0.0f - t0;
}

// ---------------- launch ----------------

extern "C" void kernel_launch(void* const* d_in, const int* in_sizes, int n_in,
                              void* d_out, int out_size, void* d_ws, size_t ws_size,
                              hipStream_t stream) {
    const float* bbx  = (const float*)d_in[0];   // [N,3,7]
    const float* tint = (const float*)d_in[1];   // [C*3]
    const int*   cnt  = (const int*)d_in[2];     // [C]
    float* out = (float*)d_out;

    const int N = in_sizes[0] / 21;
    const int C = in_sizes[2];

    const int nb     = (C + SCAN_BS - 1) / SCAN_BS;
    const int nWaves = (N + WAVE_OBJ - 1) / WAVE_OBJ;
    const int nob    = (nWaves * WAVE_OBJ + MOT_BS - 1) / MOT_BS;

    // ws layout: offsets[C] | pad 64 | waveCav[nWaves] | pad 64 | chunkSum[nb]
    int* offsets  = (int*)d_ws;
    int* waveCav  = offsets + C + 64;
    int* chunkSum = waveCav + nWaves + 64;

    chunk_sum_kernel<<<nb, SCAN_BS, 0, stream>>>(cnt, C, chunkSum);
    scan_emit_kernel<<<nb, SCAN_BS, 0, stream>>>(cnt, chunkSum, C, offsets, waveCav);
    motion_kernel<<<nob, MOT_BS, 0, stream>>>(bbx, tint, offsets, waveCav, C, N, out);
}